// Round 1
// baseline (383.913 us; speedup 1.0000x reference)
//
#include <hip/hip_runtime.h>

// GroupConnected: out[b,g] = sum_k x[b, idx[g,k]] * w[g,k]
// B=8192, F=8192, G=2048, K=8. Memory-bound: x=256MB read, out=64MB write.
// Strategy: 1 block per row b. Stage x[b,:] (32 KB) in LDS (coalesced float4),
// then each thread gathers K=8 values for each of its 8 groups.

#define GC_B 8192
#define GC_F 8192
#define GC_G 2048
#define GC_K 8
#define GC_THREADS 256

__global__ __launch_bounds__(GC_THREADS) void gc_kernel(
    const float* __restrict__ x,
    const int* __restrict__ gidx,
    const float* __restrict__ w,
    float* __restrict__ out)
{
    __shared__ float xrow[GC_F];  // 32 KB

    const int b = blockIdx.x;
    const float4* __restrict__ xr4 =
        (const float4*)(x + (size_t)b * GC_F);

    // Stage full row into LDS: 8192 floats = 2048 float4; 256 threads -> 8 each.
    float4* xrow4 = (float4*)xrow;
    #pragma unroll
    for (int i = 0; i < GC_F / 4 / GC_THREADS; ++i) {
        const int p = threadIdx.x + i * GC_THREADS;
        xrow4[p] = xr4[p];
    }
    __syncthreads();

    // Each thread handles groups g = tid + 256*j, j in [0,8).
    float* orow = out + (size_t)b * GC_G;
    #pragma unroll
    for (int j = 0; j < GC_G / GC_THREADS; ++j) {
        const int g = threadIdx.x + j * GC_THREADS;
        const int4* ip = (const int4*)(gidx + g * GC_K);
        const float4* wp = (const float4*)(w + g * GC_K);
        const int4 i0 = ip[0];
        const int4 i1 = ip[1];
        const float4 w0 = wp[0];
        const float4 w1 = wp[1];
        float s = xrow[i0.x] * w0.x;
        s += xrow[i0.y] * w0.y;
        s += xrow[i0.z] * w0.z;
        s += xrow[i0.w] * w0.w;
        s += xrow[i1.x] * w1.x;
        s += xrow[i1.y] * w1.y;
        s += xrow[i1.z] * w1.z;
        s += xrow[i1.w] * w1.w;
        orow[g] = s;
    }
}

extern "C" void kernel_launch(void* const* d_in, const int* in_sizes, int n_in,
                              void* d_out, int out_size, void* d_ws, size_t ws_size,
                              hipStream_t stream) {
    const float* x = (const float*)d_in[0];
    const int* gidx = (const int*)d_in[1];
    const float* w = (const float*)d_in[2];
    float* out = (float*)d_out;

    gc_kernel<<<GC_B, GC_THREADS, 0, stream>>>(x, gidx, w, out);
}

// Round 2
// 370.356 us; speedup vs baseline: 1.0366x; 1.0366x over previous
//
#include <hip/hip_runtime.h>

// GroupConnected: out[b,g] = sum_k x[b, idx[g,k]] * w[g,k]
// B=8192, F=8192, G=2048, K=8.
// Round 2: 2 rows per block interleaved as float2 in LDS so one ds_read_b64
// gather serves both rows (halves gather instr stream + idx/w traffic).
// 512 threads, 64 KB LDS -> 2 blocks/CU = 16 waves/CU. launch_bounds caps
// VGPR at 128 to avoid the spill/serialization that killed round 1.

#define GC_B 8192
#define GC_F 8192
#define GC_G 2048
#define GC_K 8
#define GC_T 512          // threads per block
#define GC_RPB 2          // rows per block

__global__ __launch_bounds__(GC_T, 4) void gc_kernel(
    const float* __restrict__ x,
    const int* __restrict__ gidx,
    const float* __restrict__ w,
    float* __restrict__ out)
{
    // xld[f] = { x[b0][f], x[b1][f] } — 8192 float2 slots = 64 KB
    __shared__ __align__(16) float2 xld[GC_F];

    const int b0 = blockIdx.x * GC_RPB;
    const float2* __restrict__ r0 = (const float2*)(x + (size_t)b0 * GC_F);
    const float2* __restrict__ r1 = (const float2*)(x + ((size_t)b0 + 1) * GC_F);

    // Stage both rows interleaved. 4096 float2-chunks per row, 512 threads
    // -> 8 chunks each. Chunk c covers slots 2c, 2c+1; write as one float4
    // (ds_write_b128, 16B aligned).
    #pragma unroll
    for (int i = 0; i < GC_F / 2 / GC_T; ++i) {
        const int c = threadIdx.x + i * GC_T;
        const float2 a = r0[c];
        const float2 b = r1[c];
        float4 v;
        v.x = a.x; v.y = b.x; v.z = a.y; v.w = b.y;
        *(float4*)(&xld[2 * c]) = v;
    }
    __syncthreads();

    float* o0 = out + (size_t)b0 * GC_G;
    float* o1 = out + ((size_t)b0 + 1) * GC_G;

    // Each thread: 4 groups (g = tid + 512*j), 8 gathers each (ds_read_b64).
    #pragma unroll 2
    for (int j = 0; j < GC_G / GC_T; ++j) {
        const int g = threadIdx.x + j * GC_T;
        const int4* ip = (const int4*)(gidx + g * GC_K);
        const float4* wp = (const float4*)(w + g * GC_K);
        const int4 i0 = ip[0];
        const int4 i1 = ip[1];
        const float4 w0 = wp[0];
        const float4 w1 = wp[1];

        float2 v0 = xld[i0.x];
        float2 v1 = xld[i0.y];
        float2 v2 = xld[i0.z];
        float2 v3 = xld[i0.w];
        float2 v4 = xld[i1.x];
        float2 v5 = xld[i1.y];
        float2 v6 = xld[i1.z];
        float2 v7 = xld[i1.w];

        float s0 = v0.x * w0.x + v1.x * w0.y + v2.x * w0.z + v3.x * w0.w
                 + v4.x * w1.x + v5.x * w1.y + v6.x * w1.z + v7.x * w1.w;
        float s1 = v0.y * w0.x + v1.y * w0.y + v2.y * w0.z + v3.y * w0.w
                 + v4.y * w1.x + v5.y * w1.y + v6.y * w1.z + v7.y * w1.w;

        o0[g] = s0;
        o1[g] = s1;
    }
}

extern "C" void kernel_launch(void* const* d_in, const int* in_sizes, int n_in,
                              void* d_out, int out_size, void* d_ws, size_t ws_size,
                              hipStream_t stream) {
    const float* x = (const float*)d_in[0];
    const int* gidx = (const int*)d_in[1];
    const float* w = (const float*)d_in[2];
    float* out = (float*)d_out;

    gc_kernel<<<GC_B / GC_RPB, GC_T, 0, stream>>>(x, gidx, w, out);
}

// Round 3
// 370.303 us; speedup vs baseline: 1.0368x; 1.0001x over previous
//
#include <hip/hip_runtime.h>

// GroupConnected: out[b,g] = sum_k x[b, idx[g,k]] * w[g,k]
// B=8192, F=8192, G=2048, K=8.
// Round 3: stage a ROW PAIR as packed bf16 in LDS (slot f = {bf16 x[b0][f],
// bf16 x[b1][f]} in one uint32). 32 KB LDS -> 4 blocks/CU (32 waves, full
// occupancy); gather is one ds_read_b32 per 2 output rows. Precision: bf16
// rel err 2^-8 per term, 8-term dot -> absmax ~0.05 << 0.216 threshold.

#define GC_B 8192
#define GC_F 8192
#define GC_G 2048
#define GC_K 8
#define GC_T 256
#define GC_RPB 2

__device__ __forceinline__ unsigned int bf16_pack2(float fa, float fb) {
    // round-to-nearest-even bf16 of fa (low 16) and fb (high 16)
    unsigned int ua = __float_as_uint(fa);
    unsigned int ub = __float_as_uint(fb);
    unsigned int ra = ua + 0x7FFFu + ((ua >> 16) & 1u);
    unsigned int rb = ub + 0x7FFFu + ((ub >> 16) & 1u);
    return (ra >> 16) | (rb & 0xFFFF0000u);
}

__global__ __launch_bounds__(GC_T, 4) void gc_kernel(
    const float* __restrict__ x,
    const int* __restrict__ gidx,
    const float* __restrict__ w,
    float* __restrict__ out)
{
    // 8192 packed slots = 32 KB
    __shared__ __align__(16) unsigned int xld[GC_F];

    const int b0 = blockIdx.x * GC_RPB;
    const float4* __restrict__ r0 = (const float4*)(x + (size_t)b0 * GC_F);
    const float4* __restrict__ r1 = (const float4*)(x + ((size_t)b0 + 1) * GC_F);

    // Stage: 2048 float4-chunks per row, 256 threads -> 8 chunks each.
    // Chunk c covers elements [4c,4c+4) of both rows -> 4 packed slots
    // -> one ds_write_b128.
    #pragma unroll
    for (int i = 0; i < GC_F / 4 / GC_T; ++i) {
        const int c = threadIdx.x + i * GC_T;
        const float4 a = r0[c];
        const float4 b = r1[c];
        uint4 s;
        s.x = bf16_pack2(a.x, b.x);
        s.y = bf16_pack2(a.y, b.y);
        s.z = bf16_pack2(a.z, b.z);
        s.w = bf16_pack2(a.w, b.w);
        *(uint4*)(&xld[4 * c]) = s;
    }
    __syncthreads();

    float* o0 = out + (size_t)b0 * GC_G;
    float* o1 = out + ((size_t)b0 + 1) * GC_G;

    // Each thread: 8 groups (g = tid + 256*j), 8 ds_read_b32 gathers each,
    // each gather serving both output rows.
    #pragma unroll 2
    for (int j = 0; j < GC_G / GC_T; ++j) {
        const int g = threadIdx.x + j * GC_T;
        const int4* ip = (const int4*)(gidx + g * GC_K);
        const float4* wp = (const float4*)(w + g * GC_K);
        const int4 i0 = ip[0];
        const int4 i1 = ip[1];
        const float4 w0 = wp[0];
        const float4 w1 = wp[1];

        const unsigned int u0 = xld[i0.x];
        const unsigned int u1 = xld[i0.y];
        const unsigned int u2 = xld[i0.z];
        const unsigned int u3 = xld[i0.w];
        const unsigned int u4 = xld[i1.x];
        const unsigned int u5 = xld[i1.y];
        const unsigned int u6 = xld[i1.z];
        const unsigned int u7 = xld[i1.w];

        float s0, s1;
        s0  = __uint_as_float(u0 << 16) * w0.x;
        s1  = __uint_as_float(u0 & 0xFFFF0000u) * w0.x;
        s0 += __uint_as_float(u1 << 16) * w0.y;
        s1 += __uint_as_float(u1 & 0xFFFF0000u) * w0.y;
        s0 += __uint_as_float(u2 << 16) * w0.z;
        s1 += __uint_as_float(u2 & 0xFFFF0000u) * w0.z;
        s0 += __uint_as_float(u3 << 16) * w0.w;
        s1 += __uint_as_float(u3 & 0xFFFF0000u) * w0.w;
        s0 += __uint_as_float(u4 << 16) * w1.x;
        s1 += __uint_as_float(u4 & 0xFFFF0000u) * w1.x;
        s0 += __uint_as_float(u5 << 16) * w1.y;
        s1 += __uint_as_float(u5 & 0xFFFF0000u) * w1.y;
        s0 += __uint_as_float(u6 << 16) * w1.z;
        s1 += __uint_as_float(u6 & 0xFFFF0000u) * w1.z;
        s0 += __uint_as_float(u7 << 16) * w1.w;
        s1 += __uint_as_float(u7 & 0xFFFF0000u) * w1.w;

        o0[g] = s0;
        o1[g] = s1;
    }
}

extern "C" void kernel_launch(void* const* d_in, const int* in_sizes, int n_in,
                              void* d_out, int out_size, void* d_ws, size_t ws_size,
                              hipStream_t stream) {
    const float* x = (const float*)d_in[0];
    const int* gidx = (const int*)d_in[1];
    const float* w = (const float*)d_in[2];
    float* out = (float*)d_out;

    gc_kernel<<<GC_B / GC_RPB, GC_T, 0, stream>>>(x, gidx, w, out);
}

// Round 4
// 365.584 us; speedup vs baseline: 1.0501x; 1.0129x over previous
//
#include <hip/hip_runtime.h>

// GroupConnected: out[b,g] = sum_k x[b, idx[g,k]] * w[g,k]
// B=8192, F=8192, G=2048, K=8.
// Round 4: 4 rows per block packed as bf16x4 per slot (uint2). One
// ds_read_b64 gather serves FOUR output rows. 64 KB LDS, 512 threads,
// 2 blocks/CU. Discriminating test: if dur_us doesn't move vs r3 (370.3),
// the kernel component is HBM-stream-bound (256MB x + 64MB out) and the
// remaining dur_us is harness restore/poison overhead -> roofline.

#define GC_B 8192
#define GC_F 8192
#define GC_G 2048
#define GC_K 8
#define GC_T 512
#define GC_RPB 4

__device__ __forceinline__ unsigned int bf16_pack2(float fa, float fb) {
    // round-to-nearest-even bf16 of fa (low 16) and fb (high 16)
    unsigned int ua = __float_as_uint(fa);
    unsigned int ub = __float_as_uint(fb);
    unsigned int ra = ua + 0x7FFFu + ((ua >> 16) & 1u);
    unsigned int rb = ub + 0x7FFFu + ((ub >> 16) & 1u);
    return (ra >> 16) | (rb & 0xFFFF0000u);
}

__global__ __launch_bounds__(GC_T, 2) void gc_kernel(
    const float* __restrict__ x,
    const int* __restrict__ gidx,
    const float* __restrict__ w,
    float* __restrict__ out)
{
    // slot f = { pack(r0[f],r1[f]), pack(r2[f],r3[f]) } -> 8192 uint2 = 64 KB
    __shared__ __align__(16) uint2 xld[GC_F];

    const size_t b0 = (size_t)blockIdx.x * GC_RPB;
    const float4* __restrict__ r0 = (const float4*)(x + (b0 + 0) * GC_F);
    const float4* __restrict__ r1 = (const float4*)(x + (b0 + 1) * GC_F);
    const float4* __restrict__ r2 = (const float4*)(x + (b0 + 2) * GC_F);
    const float4* __restrict__ r3 = (const float4*)(x + (b0 + 3) * GC_F);

    // Stage: 2048 float4-chunks per row, 512 threads -> 4 chunks per row each.
    // Chunk c covers elements [4c,4c+4) of all 4 rows -> 4 uint2 slots = 32 B
    // contiguous -> two ds_write_b128.
    #pragma unroll
    for (int i = 0; i < GC_F / 4 / GC_T; ++i) {
        const int c = threadIdx.x + i * GC_T;
        const float4 a = r0[c];
        const float4 b = r1[c];
        const float4 cc = r2[c];
        const float4 d = r3[c];
        uint4 lo, hi;
        lo.x = bf16_pack2(a.x, b.x);
        lo.y = bf16_pack2(cc.x, d.x);
        lo.z = bf16_pack2(a.y, b.y);
        lo.w = bf16_pack2(cc.y, d.y);
        hi.x = bf16_pack2(a.z, b.z);
        hi.y = bf16_pack2(cc.z, d.z);
        hi.z = bf16_pack2(a.w, b.w);
        hi.w = bf16_pack2(cc.w, d.w);
        *(uint4*)(&xld[4 * c]) = lo;
        *(uint4*)(&xld[4 * c + 2]) = hi;
    }
    __syncthreads();

    float* o0 = out + (b0 + 0) * GC_G;
    float* o1 = out + (b0 + 1) * GC_G;
    float* o2 = out + (b0 + 2) * GC_G;
    float* o3 = out + (b0 + 3) * GC_G;

    // Each thread: 4 groups (g = tid + 512*j), 8 ds_read_b64 gathers each,
    // each serving four output rows.
    #pragma unroll 2
    for (int j = 0; j < GC_G / GC_T; ++j) {
        const int g = threadIdx.x + j * GC_T;
        const int4* ip = (const int4*)(gidx + g * GC_K);
        const float4* wp = (const float4*)(w + g * GC_K);
        const int4 i0 = ip[0];
        const int4 i1 = ip[1];
        const float4 w0 = wp[0];
        const float4 w1 = wp[1];

        float s0 = 0.f, s1 = 0.f, s2 = 0.f, s3 = 0.f;
        const int idx[8] = {i0.x, i0.y, i0.z, i0.w, i1.x, i1.y, i1.z, i1.w};
        const float wv[8] = {w0.x, w0.y, w0.z, w0.w, w1.x, w1.y, w1.z, w1.w};
        #pragma unroll
        for (int k = 0; k < 8; ++k) {
            const uint2 u = xld[idx[k]];
            const float wk = wv[k];
            s0 += __uint_as_float(u.x << 16) * wk;
            s1 += __uint_as_float(u.x & 0xFFFF0000u) * wk;
            s2 += __uint_as_float(u.y << 16) * wk;
            s3 += __uint_as_float(u.y & 0xFFFF0000u) * wk;
        }

        o0[g] = s0;
        o1[g] = s1;
        o2[g] = s2;
        o3[g] = s3;
    }
}

extern "C" void kernel_launch(void* const* d_in, const int* in_sizes, int n_in,
                              void* d_out, int out_size, void* d_ws, size_t ws_size,
                              hipStream_t stream) {
    const float* x = (const float*)d_in[0];
    const int* gidx = (const int*)d_in[1];
    const float* w = (const float*)d_in[2];
    float* out = (float*)d_out;

    gc_kernel<<<GC_B / GC_RPB, GC_T, 0, stream>>>(x, gidx, w, out);
}